// Round 1
// baseline (247.135 us; speedup 1.0000x reference)
//
#include <hip/hip_runtime.h>
#include <hip/hip_bf16.h>

#define NBT 8192      // B*T
#define NF  16
#define ND  256
#define NH  256
#define N2D 512

typedef short bf16x8 __attribute__((ext_vector_type(8)));
typedef float f32x4 __attribute__((ext_vector_type(4)));
typedef unsigned short u16x8 __attribute__((ext_vector_type(8)));
typedef unsigned short u16x4 __attribute__((ext_vector_type(4)));

__device__ __forceinline__ float bf2f(unsigned short u) {
  return __uint_as_float(((unsigned)u) << 16);
}
__device__ __forceinline__ unsigned short f2bf(float f) {
  unsigned u = __float_as_uint(f);
  return (unsigned short)((u + 0x7FFFu + ((u >> 16) & 1u)) >> 16);
}

// ---------------------------------------------------------------------------
// Weight GRN + softmax -> w [NBT][16] (fp32 exact). 8 lanes cooperate per row.
// ---------------------------------------------------------------------------
__global__ __launch_bounds__(256) void wgrn_kernel(
    const float* __restrict__ x,     // [NBT][16]
    const float* __restrict__ fw1,   // wg_fc1_w [16][256]
    const float* __restrict__ fb1,   // [256]
    const float* __restrict__ fw2,   // wg_fc2_w [256][16]
    const float* __restrict__ fb2,   // [16]
    const float* __restrict__ gwt,   // wg_glu_w [16][32]
    const float* __restrict__ gbt,   // [32]
    const float* __restrict__ lng,   // [16]
    const float* __restrict__ lnb,   // [16]
    float* __restrict__ wout)        // [NBT][16]
{
  __shared__ float w1t[256 * 16];    // [j][f]
  __shared__ float w2s[256 * 16];    // [j][g]
  const int tid = threadIdx.x;
  for (int i = tid; i < 4096; i += 256) {
    int ff = i >> 8, j = i & 255;
    w1t[j * 16 + ff] = fw1[i];
    w2s[i] = fw2[i];
  }
  __syncthreads();

  const int sub  = tid & 7;
  const int rowi = tid >> 3;               // 32 rows per block
  const int bt   = blockIdx.x * 32 + rowi; // grid = 256 blocks

  float xr[16];
#pragma unroll
  for (int i = 0; i < 4; ++i)
    *(float4*)&xr[i * 4] = *(const float4*)(x + (size_t)bt * 16 + i * 4);

  float acc2[16];
#pragma unroll
  for (int q = 0; q < 16; ++q) acc2[q] = 0.f;

  for (int j = sub; j < 256; j += 8) {
    float h = fb1[j];
    const float* wr = &w1t[j * 16];
#pragma unroll
    for (int q = 0; q < 16; ++q) h = fmaf(xr[q], wr[q], h);
    h = h > 0.f ? h : expm1f(h);
    const float* w2r = &w2s[j * 16];
#pragma unroll
    for (int q = 0; q < 16; ++q) acc2[q] = fmaf(h, w2r[q], acc2[q]);
  }
#pragma unroll
  for (int off = 1; off < 8; off <<= 1) {
#pragma unroll
    for (int q = 0; q < 16; ++q) acc2[q] += __shfl_xor(acc2[q], off);
  }
#pragma unroll
  for (int q = 0; q < 16; ++q) acc2[q] += fb2[q];

  float gw[32];
#pragma unroll
  for (int k = 0; k < 32; ++k) {
    float s = gbt[k];
#pragma unroll
    for (int q = 0; q < 16; ++q) s = fmaf(acc2[q], gwt[q * 32 + k], s);
    gw[k] = s;
  }

  float v[16];
  float mean = 0.f;
#pragma unroll
  for (int q = 0; q < 16; ++q) {
    float sg = 1.f / (1.f + __expf(-gw[16 + q]));
    v[q] = fmaf(gw[q], sg, xr[q]);
    mean += v[q];
  }
  mean *= (1.f / 16.f);
  float var = 0.f;
#pragma unroll
  for (int q = 0; q < 16; ++q) { float d = v[q] - mean; var = fmaf(d, d, var); }
  var *= (1.f / 16.f);
  float rstd = rsqrtf(var + 1e-5f);
  float mx = -1e30f;
#pragma unroll
  for (int q = 0; q < 16; ++q) {
    v[q] = (v[q] - mean) * rstd * lng[q] + lnb[q];
    mx = fmaxf(mx, v[q]);
  }
  float se = 0.f;
#pragma unroll
  for (int q = 0; q < 16; ++q) { v[q] = __expf(v[q] - mx); se += v[q]; }
  float inv = 1.f / se;
  if (sub == 0) {
#pragma unroll
    for (int i = 0; i < 4; ++i) {
      float4 o = { v[i*4+0]*inv, v[i*4+1]*inv, v[i*4+2]*inv, v[i*4+3]*inv };
      *(float4*)(wout + (size_t)bt * 16 + i * 4) = o;
    }
  }
}

// ---------------------------------------------------------------------------
// fp32 [F][K][N] -> bf16 [F][N][K] tiled transpose+cast
// ---------------------------------------------------------------------------
__global__ void transpose_cast(const float* __restrict__ src,
                               unsigned short* __restrict__ dst, int K, int N) {
  __shared__ float tile[32][33];
  const int f = blockIdx.z;
  const float* s = src + (size_t)f * K * N;
  unsigned short* d = dst + (size_t)f * K * N;
  const int k0 = blockIdx.y * 32, n0 = blockIdx.x * 32;
  const int tx = threadIdx.x, ty = threadIdx.y;
#pragma unroll
  for (int i = 0; i < 32; i += 8)
    tile[ty + i][tx] = s[(size_t)(k0 + ty + i) * N + n0 + tx];
  __syncthreads();
#pragma unroll
  for (int i = 0; i < 32; i += 8)
    d[(size_t)(n0 + ty + i) * K + k0 + tx] = f2bf(tile[tx][ty + i]);
}

// ---------------------------------------------------------------------------
// h0 = relu(x*w1 + b1) -> bf16 [F][NBT][ND]
// ---------------------------------------------------------------------------
__global__ __launch_bounds__(256) void h0_kernel(
    const float* __restrict__ x, const float* __restrict__ w1,
    const float* __restrict__ b1, unsigned short* __restrict__ h0) {
  size_t idx = (size_t)blockIdx.x * 256 + threadIdx.x;
  size_t e = idx * 8;
  int f = (int)(e / ((size_t)NBT * ND));
  size_t r = e % ((size_t)NBT * ND);
  int bt = (int)(r / ND);
  int d  = (int)(r % ND);
  float xv = x[(size_t)bt * NF + f];
  const float* wp = w1 + f * ND + d;
  const float* bp = b1 + f * ND + d;
  float4 w0 = *(const float4*)wp,      w4 = *(const float4*)(wp + 4);
  float4 c0 = *(const float4*)bp,      c4 = *(const float4*)(bp + 4);
  u16x8 o;
  o[0] = f2bf(fmaxf(fmaf(xv, w0.x, c0.x), 0.f));
  o[1] = f2bf(fmaxf(fmaf(xv, w0.y, c0.y), 0.f));
  o[2] = f2bf(fmaxf(fmaf(xv, w0.z, c0.z), 0.f));
  o[3] = f2bf(fmaxf(fmaf(xv, w0.w, c0.w), 0.f));
  o[4] = f2bf(fmaxf(fmaf(xv, w4.x, c4.x), 0.f));
  o[5] = f2bf(fmaxf(fmaf(xv, w4.y, c4.y), 0.f));
  o[6] = f2bf(fmaxf(fmaf(xv, w4.z, c4.z), 0.f));
  o[7] = f2bf(fmaxf(fmaf(xv, w4.w, c4.w), 0.f));
  *(u16x8*)(h0 + e) = o;
}

// ---------------------------------------------------------------------------
// Grouped GEMM: C[f] = epi(A[f] @ B[f]^T + bias[f]), bf16 in/out, fp32 acc
// A [F][M][K], Bw [F][N][K] (pre-transposed), C [F][M][N]
// 128x128 tile, BK=64, 4 waves (2x2), gload_lds + XOR swizzle (G4/rule21)
// EPI: 0 = bias only, 1 = bias + ELU
// ---------------------------------------------------------------------------
#define BM 128
#define BN 128
#define BKK 64

template <int EPI>
__global__ __launch_bounds__(256, 2) void gemm_bf16(
    const unsigned short* __restrict__ A, const unsigned short* __restrict__ Bw,
    const float* __restrict__ bias, unsigned short* __restrict__ C,
    int M, int N, int K) {
  __shared__ __align__(16) unsigned short ldsA[BM * BKK];
  __shared__ __align__(16) unsigned short ldsB[BN * BKK];
  const int tid  = threadIdx.x;
  const int lane = tid & 63;
  const int wid  = tid >> 6;
  const int f    = blockIdx.z;
  const int m0   = blockIdx.y * BM;
  const int n0   = blockIdx.x * BN;
  const unsigned short* Af = A + (size_t)f * M * K;
  const unsigned short* Bf = Bw + (size_t)f * N * K;
  const int wm = (wid >> 1) * 64;
  const int wn = (wid & 1) * 64;

  f32x4 acc[4][4];
#pragma unroll
  for (int m = 0; m < 4; ++m)
#pragma unroll
    for (int n = 0; n < 4; ++n) acc[m][n] = (f32x4){0.f, 0.f, 0.f, 0.f};

  const int kc = lane >> 4;   // 0..3 : which 8-elem K chunk
  const int rl = lane & 15;

  for (int kt = 0; kt < K; kt += BKK) {
    __syncthreads();   // previous tile fully consumed before new writes land
#pragma unroll
    for (int i = 0; i < 4; ++i) {
      int s = tid + 256 * i;           // slot 0..1023 (16B slots)
      int row = s >> 3, sl = s & 7;
      int srcoff = ((sl ^ (row & 7)) << 3);  // inverse-swizzled source (elems)
      const unsigned short* ga = Af + (size_t)(m0 + row) * K + kt + srcoff;
      const unsigned short* gb = Bf + (size_t)(n0 + row) * K + kt + srcoff;
      char* la = (char*)ldsA + (wid * 64 + 256 * i) * 16;  // wave-uniform base
      char* lb = (char*)ldsB + (wid * 64 + 256 * i) * 16;
      __builtin_amdgcn_global_load_lds(
          (const __attribute__((address_space(1))) unsigned int*)ga,
          (__attribute__((address_space(3))) unsigned int*)la, 16, 0, 0);
      __builtin_amdgcn_global_load_lds(
          (const __attribute__((address_space(1))) unsigned int*)gb,
          (__attribute__((address_space(3))) unsigned int*)lb, 16, 0, 0);
    }
    __syncthreads();   // implies vmcnt(0): staged data visible

#pragma unroll
    for (int kk = 0; kk < 2; ++kk) {
      bf16x8 av[4], bv[4];
#pragma unroll
      for (int m = 0; m < 4; ++m) {
        int rr = wm + m * 16 + rl;
        int sl = ((kk << 2) | kc) ^ (rr & 7);
        av[m] = *(const bf16x8*)((const char*)ldsA + rr * 128 + sl * 16);
      }
#pragma unroll
      for (int n = 0; n < 4; ++n) {
        int rr = wn + n * 16 + rl;
        int sl = ((kk << 2) | kc) ^ (rr & 7);
        bv[n] = *(const bf16x8*)((const char*)ldsB + rr * 128 + sl * 16);
      }
#pragma unroll
      for (int m = 0; m < 4; ++m)
#pragma unroll
        for (int n = 0; n < 4; ++n)
          acc[m][n] = __builtin_amdgcn_mfma_f32_16x16x32_bf16(
              av[m], bv[n], acc[m][n], 0, 0, 0);
    }
  }

  const int rq = lane >> 4;
#pragma unroll
  for (int n = 0; n < 4; ++n) {
    int c = n0 + wn + n * 16 + rl;
    float bvv = bias[f * N + c];
#pragma unroll
    for (int m = 0; m < 4; ++m) {
#pragma unroll
      for (int j = 0; j < 4; ++j) {
        int r = m0 + wm + m * 16 + rq * 4 + j;
        float v = acc[m][n][j] + bvv;
        if (EPI == 1) v = v > 0.f ? v : expm1f(v);
        C[(size_t)f * M * N + (size_t)r * N + c] = f2bf(v);
      }
    }
  }
}

// ---------------------------------------------------------------------------
// GLU epilogue + LayerNorm: H = LN(h0 + a*sigmoid(gate)) -> bf16 [F][NBT][ND]
// one wave per (f,bt) row; h0 recomputed in fp32
// ---------------------------------------------------------------------------
__global__ __launch_bounds__(256) void glu_ln_kernel(
    const unsigned short* __restrict__ g,   // [F][NBT][512]
    const float* __restrict__ x, const float* __restrict__ w1,
    const float* __restrict__ b1, const float* __restrict__ lng,
    const float* __restrict__ lnb, unsigned short* __restrict__ Hout) {
  const int R = blockIdx.x * 4 + (threadIdx.x >> 6);
  const int lane = threadIdx.x & 63;
  const int f  = R >> 13;          // R / NBT
  const int bt = R & (NBT - 1);
  const unsigned short* gr = g + (size_t)R * N2D;
  const int d0 = lane * 4;
  float xv = x[(size_t)bt * NF + f];
  float4 wv = *(const float4*)(w1 + f * ND + d0);
  float4 bv = *(const float4*)(b1 + f * ND + d0);
  u16x4 au = *(const u16x4*)(gr + d0);
  u16x4 gu = *(const u16x4*)(gr + ND + d0);
  float wj[4] = {wv.x, wv.y, wv.z, wv.w};
  float bj[4] = {bv.x, bv.y, bv.z, bv.w};
  float va[4];
  float s = 0.f, s2 = 0.f;
#pragma unroll
  for (int j = 0; j < 4; ++j) {
    float h0 = fmaxf(fmaf(xv, wj[j], bj[j]), 0.f);
    float av = bf2f(au[j]);
    float gv = bf2f(gu[j]);
    float sg = 1.f / (1.f + __expf(-gv));
    va[j] = fmaf(av, sg, h0);
    s += va[j];
    s2 = fmaf(va[j], va[j], s2);
  }
#pragma unroll
  for (int off = 1; off < 64; off <<= 1) {
    s  += __shfl_xor(s, off);
    s2 += __shfl_xor(s2, off);
  }
  float mean = s * (1.f / 256.f);
  float var  = s2 * (1.f / 256.f) - mean * mean;
  float rstd = rsqrtf(var + 1e-5f);
  float4 gg = *(const float4*)(lng + f * ND + d0);
  float4 bb = *(const float4*)(lnb + f * ND + d0);
  float gj[4] = {gg.x, gg.y, gg.z, gg.w};
  float cj[4] = {bb.x, bb.y, bb.z, bb.w};
  u16x4 o;
#pragma unroll
  for (int j = 0; j < 4; ++j)
    o[j] = f2bf(fmaf((va[j] - mean) * rstd, gj[j], cj[j]));
  *(u16x4*)(Hout + (size_t)R * ND + d0) = o;
}

// ---------------------------------------------------------------------------
// z[bt][d] = sum_f H[f][bt][d] * w[bt][f]
// ---------------------------------------------------------------------------
__global__ __launch_bounds__(256) void combine_kernel(
    const unsigned short* __restrict__ H,  // [F][NBT][ND]
    const float* __restrict__ w,           // [NBT][16]
    float* __restrict__ z) {               // [NBT][ND]
  int idx = blockIdx.x * 256 + threadIdx.x;
  int bt = idx >> 5;
  int d  = (idx & 31) << 3;
  float a[8];
#pragma unroll
  for (int j = 0; j < 8; ++j) a[j] = 0.f;
#pragma unroll
  for (int f = 0; f < 16; ++f) {
    u16x8 hv = *(const u16x8*)(H + ((size_t)f * NBT + bt) * ND + d);
    float wvv = w[bt * 16 + f];
#pragma unroll
    for (int j = 0; j < 8; ++j) a[j] = fmaf(bf2f(hv[j]), wvv, a[j]);
  }
  float4 o0 = {a[0], a[1], a[2], a[3]};
  float4 o1 = {a[4], a[5], a[6], a[7]};
  *(float4*)(z + (size_t)bt * ND + d)     = o0;
  *(float4*)(z + (size_t)bt * ND + d + 4) = o1;
}

// ---------------------------------------------------------------------------
extern "C" void kernel_launch(void* const* d_in, const int* in_sizes, int n_in,
                              void* d_out, int out_size, void* d_ws,
                              size_t ws_size, hipStream_t stream) {
  const float* x        = (const float*)d_in[0];
  const float* w1       = (const float*)d_in[1];
  const float* b1       = (const float*)d_in[2];
  const float* fc1_w    = (const float*)d_in[3];
  const float* fc1_b    = (const float*)d_in[4];
  const float* fc2_w    = (const float*)d_in[5];
  const float* fc2_b    = (const float*)d_in[6];
  const float* glu_w    = (const float*)d_in[7];
  const float* glu_b    = (const float*)d_in[8];
  const float* ln_g     = (const float*)d_in[9];
  const float* ln_b     = (const float*)d_in[10];
  const float* wg_fc1_w = (const float*)d_in[11];
  const float* wg_fc1_b = (const float*)d_in[12];
  const float* wg_fc2_w = (const float*)d_in[13];
  const float* wg_fc2_b = (const float*)d_in[14];
  const float* wg_glu_w = (const float*)d_in[15];
  const float* wg_glu_b = (const float*)d_in[16];
  const float* wg_ln_g  = (const float*)d_in[17];
  const float* wg_ln_b  = (const float*)d_in[18];

  char* ws = (char*)d_ws;
  const size_t SZ_A = (size_t)NF * NBT * ND * 2;   // 67 MB  ping
  const size_t SZ_B = (size_t)NF * NBT * N2D * 2;  // 134 MB pong
  unsigned short* wsA  = (unsigned short*)ws;                 // h0 -> y2 -> H
  unsigned short* wsB  = (unsigned short*)(ws + SZ_A);        // y1 -> g
  unsigned short* fc1t = (unsigned short*)(ws + SZ_A + SZ_B);
  unsigned short* fc2t = fc1t + (size_t)NF * NH * ND;
  unsigned short* glut = fc2t + (size_t)NF * ND * NH;

  float* zout = (float*)d_out;                 // [NBT][ND]
  float* wout = zout + (size_t)NBT * ND;       // [NBT][16]

  // weight GRN -> w (fp32, exact)
  wgrn_kernel<<<256, 256, 0, stream>>>(x, wg_fc1_w, wg_fc1_b, wg_fc2_w,
                                       wg_fc2_b, wg_glu_w, wg_glu_b, wg_ln_g,
                                       wg_ln_b, wout);
  // transpose+cast weights to [N][K] bf16
  transpose_cast<<<dim3(8, 8, NF),  dim3(32, 8), 0, stream>>>(fc1_w, fc1t, ND, NH);
  transpose_cast<<<dim3(8, 8, NF),  dim3(32, 8), 0, stream>>>(fc2_w, fc2t, NH, ND);
  transpose_cast<<<dim3(16, 8, NF), dim3(32, 8), 0, stream>>>(glu_w, glut, ND, N2D);
  // h0
  h0_kernel<<<16384, 256, 0, stream>>>(x, w1, b1, wsA);
  // fc1 + ELU : y1 = elu(h0 @ fc1_w + b)    [F][NBT][NH]
  gemm_bf16<1><<<dim3(NH / BN, NBT / BM, NF), 256, 0, stream>>>(
      wsA, fc1t, fc1_b, wsB, NBT, NH, ND);
  // fc2 : y2 = y1 @ fc2_w + b               [F][NBT][ND]  (h0 dead -> wsA)
  gemm_bf16<0><<<dim3(ND / BN, NBT / BM, NF), 256, 0, stream>>>(
      wsB, fc2t, fc2_b, wsA, NBT, ND, NH);
  // glu : g = y2 @ glu_w + b                [F][NBT][512] (y1 dead -> wsB)
  gemm_bf16<0><<<dim3(N2D / BN, NBT / BM, NF), 256, 0, stream>>>(
      wsA, glut, glu_b, wsB, NBT, N2D, ND);
  // H = LN(h0 + a*sigmoid(gate))            (y2 dead -> wsA)
  glu_ln_kernel<<<(NF * NBT) / 4, 256, 0, stream>>>(wsB, x, w1, b1, ln_g, ln_b,
                                                    wsA);
  // z = sum_f H * w
  combine_kernel<<<(NBT * ND / 8) / 256, 256, 0, stream>>>(wsA, wout, zout);

  (void)in_sizes; (void)n_in; (void)out_size; (void)ws_size;
}